// Round 4
// baseline (821.632 us; speedup 1.0000x reference)
//
#include <hip/hip_runtime.h>
#include <cstdint>

#define B_  128
#define S_  1024
#define U_  1024
#define IN_ 64

typedef unsigned short u16;
typedef __attribute__((ext_vector_type(8))) short short8v;
typedef __attribute__((ext_vector_type(4))) float f32x4;

__device__ __forceinline__ u16 f2bf(float f) {
  uint32_t u = __builtin_bit_cast(uint32_t, f);
  u += 0x7fffu + ((u >> 16) & 1u);
  return (u16)(u >> 16);
}
__device__ __forceinline__ float bf2f(u16 h) {
  uint32_t u = ((uint32_t)h) << 16;
  return __builtin_bit_cast(float, u);
}
// tanh via hw exp + rcp: ~6 VALU ops, |err| ~1e-5 (way under bf16 budget)
__device__ __forceinline__ float fast_tanh(float x) {
  float e = __expf(2.0f * x);
  return 1.0f - 2.0f * __builtin_amdgcn_rcpf(e + 1.0f);
}

// ---------------- enc f32 -> bf16 ----------------
__global__ void conv_enc_k(const float* __restrict__ in, u16* __restrict__ out) {
  size_t tid = (size_t)blockIdx.x * blockDim.x + threadIdx.x;
  size_t stride = (size_t)gridDim.x * blockDim.x;
  const size_t n8 = (size_t)B_ * S_ * U_ / 8;
  for (size_t p = tid; p < n8; p += stride) {
    const float* src = in + p * 8;
    float4 a = *(const float4*)src;
    float4 b = *(const float4*)(src + 4);
    short8v h;
    h[0] = (short)f2bf(a.x); h[1] = (short)f2bf(a.y);
    h[2] = (short)f2bf(a.z); h[3] = (short)f2bf(a.w);
    h[4] = (short)f2bf(b.x); h[5] = (short)f2bf(b.y);
    h[6] = (short)f2bf(b.z); h[7] = (short)f2bf(b.w);
    *(short8v*)(out + p * 8) = h;
  }
}

// ---------------- W1 (K x N) -> W1^T bf16 (N x K) ----------------
__global__ void conv_w1t_k(const float* __restrict__ W1, u16* __restrict__ w1t) {
  __shared__ float tile[32][33];
  int tx = threadIdx.x & 31, tg = threadIdx.x >> 5;  // 32 x 8
  int nb = blockIdx.x << 5, kb = blockIdx.y << 5;
#pragma unroll
  for (int i = 0; i < 4; ++i)
    tile[tg + i * 8][tx] = W1[(size_t)(kb + tg + i * 8) * U_ + nb + tx];
  __syncthreads();
#pragma unroll
  for (int i = 0; i < 4; ++i)
    w1t[(size_t)(nb + tg + i * 8) * U_ + kb + tx] = f2bf(tile[tx][tg + i * 8]);
}

// ---------------- fused score GEMM v3: 256x256 tile, frag double-buffer ----
// score[r] = sum_n tanh( (enc @ W1)[r,n] + b1[n] + b2[n] + hb[b(r),n] ) * V[n]
// 8 waves (2M x 4N), per-wave 128x64 output, BK=32, 4 LDS buffers (128 KB),
// global_load_lds prefetch depth 3. Per iter t:
//   vmcnt(4)   -> this wave's tile-(t+1) loads done (issued at t-2, ~free)
//   s_barrier  -> ALL waves' tile-(t+1) stage writes globally visible
//   stage(t+3) -> writes buf[(t-1)&3]; its last readers ran at iter t-2
//   ds_read frags(t+1)  (no consumer this iter -> hides under MFMA)
//   32 MFMA on frags(t) (register set from previous iter)
// Unrolled x2 with named register sets A/B (static indexing).
__global__ __launch_bounds__(512, 1) void score_gemm2_k(
    const u16* __restrict__ encb, const u16* __restrict__ w1t,
    const float* __restrict__ hb, const float* __restrict__ b1,
    const float* __restrict__ b2, const float* __restrict__ Vv,
    float* __restrict__ score)
{
  __shared__ __align__(16) char lds[131072];   // 4 bufs x (A 16KB + B 16KB)
  const int tid  = threadIdx.x;
  const int lane = tid & 63;
  const int wid  = tid >> 6;                   // 0..7
  const int wm = wid >> 2, wn = wid & 3;
  const int r16 = lane & 15, g4 = lane >> 4;

  // XCD-aware bijective swizzle (2048 % 8 == 0), n-inner for A-tile L2 reuse
  int bid = blockIdx.x;
  int logical = (bid & 7) * 256 + (bid >> 3);
  const int row0 = (logical >> 2) << 8;        // M-tile * 256
  const int n0   = (logical & 3) << 8;         // N-tile * 256

  // read-side constants: chunk = g4 ^ ((r16>>1)&3), invariant across mi/ni
  const int cx   = (g4 ^ ((r16 >> 1) & 3)) << 4;
  const int aoff = wm * 8192 + r16 * 64 + cx;          // + mi*1024
  const int boff = 16384 + wn * 4096 + r16 * 64 + cx;  // + ni*1024
  const int qA   = wid << 1;                           // stage issues qA, qA+1

  f32x4 acc[8][4] = {};
  short8v afA[8], bfA[4], afB[8], bfB[4];

  auto stage = [&](int tk) {
    const int base = (tk & 3) << 15;
    const int kk = tk << 5;
#pragma unroll
    for (int i = 0; i < 2; ++i) {
      int q = qA + i;                       // 0..15
      int cg = (q << 6) + lane;             // 0..1023 16B-chunks
      int row = cg >> 2, c = cg & 3;
      int j = c ^ ((row >> 1) & 3);
      const u16* srcA = encb + (((size_t)(row0 + row)) << 10) + kk + (j << 3);
      __builtin_amdgcn_global_load_lds(
          (const __attribute__((address_space(1))) void*)srcA,
          (__attribute__((address_space(3))) void*)(lds + base + (q << 10)), 16, 0, 0);
      const u16* srcB = w1t + (((size_t)(n0 + row)) << 10) + kk + (j << 3);
      __builtin_amdgcn_global_load_lds(
          (const __attribute__((address_space(1))) void*)srcB,
          (__attribute__((address_space(3))) void*)(lds + base + 16384 + (q << 10)), 16, 0, 0);
    }
  };

  auto loadfrag = [&](short8v (&af)[8], short8v (&bf)[4], int tk) {
    const char* base = lds + ((tk & 3) << 15);
#pragma unroll
    for (int mi = 0; mi < 8; ++mi)
      af[mi] = *(const short8v*)(base + aoff + mi * 1024);
#pragma unroll
    for (int ni = 0; ni < 4; ++ni)
      bf[ni] = *(const short8v*)(base + boff + ni * 1024);
  };

  auto compute = [&](short8v (&af)[8], short8v (&bf)[4]) {
    __builtin_amdgcn_s_setprio(1);
#pragma unroll
    for (int mi = 0; mi < 8; ++mi)
#pragma unroll
      for (int ni = 0; ni < 4; ++ni)
        acc[mi][ni] = __builtin_amdgcn_mfma_f32_16x16x32_bf16(af[mi], bf[ni], acc[mi][ni], 0, 0, 0);
    __builtin_amdgcn_s_setprio(0);
  };

  // prologue: 3 tiles in flight; tile 0 visible to all waves; frags(0) -> A
  stage(0); stage(1); stage(2);
  asm volatile("s_waitcnt vmcnt(8)" ::: "memory");
  __builtin_amdgcn_s_barrier();
  __builtin_amdgcn_sched_barrier(0);
  loadfrag(afA, bfA, 0);

  // main loop: t = 0..27, unrolled x2 (even t computes A / loads B, odd flips)
  for (int t = 0; t < 28; t += 2) {
    asm volatile("s_waitcnt vmcnt(4)" ::: "memory");
    __builtin_amdgcn_s_barrier();
    __builtin_amdgcn_sched_barrier(0);
    stage(t + 3);
    loadfrag(afB, bfB, t + 1);
    compute(afA, bfA);

    asm volatile("s_waitcnt vmcnt(4)" ::: "memory");
    __builtin_amdgcn_s_barrier();
    __builtin_amdgcn_sched_barrier(0);
    stage(t + 4);
    loadfrag(afA, bfA, t + 2);
    compute(afB, bfB);
  }
  // t = 28 (stages tile 31, the last)
  asm volatile("s_waitcnt vmcnt(4)" ::: "memory");
  __builtin_amdgcn_s_barrier();
  __builtin_amdgcn_sched_barrier(0);
  stage(31);
  loadfrag(afB, bfB, 29);
  compute(afA, bfA);
  // t = 29
  asm volatile("s_waitcnt vmcnt(4)" ::: "memory");
  __builtin_amdgcn_s_barrier();
  __builtin_amdgcn_sched_barrier(0);
  loadfrag(afA, bfA, 30);
  compute(afB, bfB);
  // t = 30
  asm volatile("s_waitcnt vmcnt(0)" ::: "memory");
  __builtin_amdgcn_s_barrier();
  __builtin_amdgcn_sched_barrier(0);
  loadfrag(afB, bfB, 31);
  compute(afA, bfA);
  // t = 31
  compute(afB, bfB);

  // ---- epilogue: tanh(+hb+b1+b2) * V, row-reduce over 16 lanes, atomicAdd ----
  const int b = row0 >> 10;                 // 256-row tile never crosses batch
  float vv[4], hbv[4];
#pragma unroll
  for (int ni = 0; ni < 4; ++ni) {
    int col = n0 + (wn << 6) + (ni << 4) + r16;
    vv[ni]  = Vv[col];
    hbv[ni] = hb[(b << 10) + col] + b1[col] + b2[col];
  }
  float rowsum[8][4];
#pragma unroll
  for (int mi = 0; mi < 8; ++mi)
#pragma unroll
    for (int j = 0; j < 4; ++j) rowsum[mi][j] = 0.0f;
#pragma unroll
  for (int mi = 0; mi < 8; ++mi)
#pragma unroll
    for (int ni = 0; ni < 4; ++ni)
#pragma unroll
      for (int j = 0; j < 4; ++j)
        rowsum[mi][j] += fast_tanh(acc[mi][ni][j] + hbv[ni]) * vv[ni];
#pragma unroll
  for (int mi = 0; mi < 8; ++mi)
#pragma unroll
    for (int j = 0; j < 4; ++j) {
      float rs = rowsum[mi][j];
      rs += __shfl_xor(rs, 1);
      rs += __shfl_xor(rs, 2);
      rs += __shfl_xor(rs, 4);
      rs += __shfl_xor(rs, 8);
      if (r16 == 0)
        atomicAdd(score + row0 + (wm << 7) + (mi << 4) + (g4 << 2) + j, rs);
    }
}

// ---------------- fallback fp32-input score GEMM (path B only) ----------------
__global__ __launch_bounds__(256) void score_gemm_f32_k(
    const float* __restrict__ encf, const u16* __restrict__ w1t,
    const float* __restrict__ hb, const float* __restrict__ b1,
    const float* __restrict__ b2, const float* __restrict__ Vv,
    float* __restrict__ score)
{
  __shared__ __align__(16) char lds[32768];
  const int tid  = threadIdx.x;
  const int lane = tid & 63;
  const int wid  = tid >> 6;
  const int wm = wid >> 1, wn = wid & 1;
  const int r16 = lane & 15, g4 = lane >> 4;
  int bid = blockIdx.x;
  int logical = (bid & 7) * 1024 + (bid >> 3);
  const int row0 = (logical >> 3) << 7;
  const int n0   = (logical & 7) << 7;
  f32x4 acc[4][4] = {};
  for (int kk = 0; kk < U_; kk += 64) {
#pragma unroll
    for (int qi = 0; qi < 4; ++qi) {
      int q = 16 + wid * 4 + qi;
      int n = ((q - 16) << 3) + (lane >> 3);
      int c = lane & 7;
      int j = c ^ (n & 7);
      const u16* src = w1t + (((size_t)(n0 + n)) << 10) + kk + (j << 3);
      __builtin_amdgcn_global_load_lds(
          (const __attribute__((address_space(1))) void*)src,
          (__attribute__((address_space(3))) void*)(lds + (q << 10)), 16, 0, 0);
    }
#pragma unroll
    for (int i = 0; i < 4; ++i) {
      int cg = tid * 4 + i;
      int r = cg >> 3, c = cg & 7;
      int j = c ^ (r & 7);
      const float* g = encf + (((size_t)(row0 + r)) << 10) + kk + (j << 3);
      float4 a = *(const float4*)g;
      float4 b = *(const float4*)(g + 4);
      short8v h;
      h[0] = (short)f2bf(a.x); h[1] = (short)f2bf(a.y);
      h[2] = (short)f2bf(a.z); h[3] = (short)f2bf(a.w);
      h[4] = (short)f2bf(b.x); h[5] = (short)f2bf(b.y);
      h[6] = (short)f2bf(b.z); h[7] = (short)f2bf(b.w);
      *(short8v*)(lds + (cg << 4)) = h;
    }
    __syncthreads();
#pragma unroll
    for (int ks = 0; ks < 2; ++ks) {
      short8v af[4], bf[4];
#pragma unroll
      for (int mi = 0; mi < 4; ++mi) {
        int row = (wm << 6) + (mi << 4) + r16;
        int jx = (ks << 2) + g4;
        af[mi] = *(const short8v*)(lds + (row << 7) + ((jx ^ (row & 7)) << 4));
      }
#pragma unroll
      for (int ni = 0; ni < 4; ++ni) {
        int n = (wn << 6) + (ni << 4) + r16;
        int jx = (ks << 2) + g4;
        bf[ni] = *(const short8v*)(lds + 16384 + (n << 7) + ((jx ^ (n & 7)) << 4));
      }
#pragma unroll
      for (int mi = 0; mi < 4; ++mi)
#pragma unroll
        for (int ni = 0; ni < 4; ++ni)
          acc[mi][ni] = __builtin_amdgcn_mfma_f32_16x16x32_bf16(af[mi], bf[ni], acc[mi][ni], 0, 0, 0);
    }
    __syncthreads();
  }
  const int b = row0 >> 10;
  float vv[4], hbv[4];
#pragma unroll
  for (int ni = 0; ni < 4; ++ni) {
    int col = n0 + (wn << 6) + (ni << 4) + r16;
    vv[ni]  = Vv[col];
    hbv[ni] = hb[(b << 10) + col] + b1[col] + b2[col];
  }
  float rowsum[4][4];
#pragma unroll
  for (int mi = 0; mi < 4; ++mi)
#pragma unroll
    for (int j = 0; j < 4; ++j) rowsum[mi][j] = 0.0f;
#pragma unroll
  for (int mi = 0; mi < 4; ++mi)
#pragma unroll
    for (int ni = 0; ni < 4; ++ni)
#pragma unroll
      for (int j = 0; j < 4; ++j)
        rowsum[mi][j] += fast_tanh(acc[mi][ni][j] + hbv[ni]) * vv[ni];
#pragma unroll
  for (int mi = 0; mi < 4; ++mi)
#pragma unroll
    for (int j = 0; j < 4; ++j) {
      float rs = rowsum[mi][j];
      rs += __shfl_xor(rs, 1);
      rs += __shfl_xor(rs, 2);
      rs += __shfl_xor(rs, 4);
      rs += __shfl_xor(rs, 8);
      if (r16 == 0)
        atomicAdd(score + row0 + (wm << 6) + (mi << 4) + (g4 << 2) + j, rs);
    }
}

// ---------------- softmax over S per batch ----------------
__global__ void softmax_k(const float* __restrict__ score, float* __restrict__ attn) {
  __shared__ float red[8];
  int b = blockIdx.x, t = threadIdx.x;     // 256 threads, 4 vals each
  float4 v = ((const float4*)(score + ((size_t)b << 10)))[t];
  float m = fmaxf(fmaxf(v.x, v.y), fmaxf(v.z, v.w));
  for (int o = 1; o < 64; o <<= 1) m = fmaxf(m, __shfl_xor(m, o));
  if ((t & 63) == 0) red[t >> 6] = m;
  __syncthreads();
  m = fmaxf(fmaxf(red[0], red[1]), fmaxf(red[2], red[3]));
  float e0 = expf(v.x - m), e1 = expf(v.y - m), e2 = expf(v.z - m), e3 = expf(v.w - m);
  float s = e0 + e1 + e2 + e3;
  for (int o = 1; o < 64; o <<= 1) s += __shfl_xor(s, o);
  if ((t & 63) == 0) red[4 + (t >> 6)] = s;
  __syncthreads();
  s = red[4] + red[5] + red[6] + red[7];
  float inv = 1.0f / s;
  float4 o4; o4.x = e0 * inv; o4.y = e1 * inv; o4.z = e2 * inv; o4.w = e3 * inv;
  ((float4*)(attn + ((size_t)b << 10)))[t] = o4;
}

// ---------------- context = attn^T @ enc  (accumulate into gin[:, :1024]) ----------------
template<bool ABF16>
__global__ void context_k(const void* __restrict__ encp, const float* __restrict__ attn,
                          float* __restrict__ gin) {
  __shared__ float aw[128];
  int b = blockIdx.x >> 3, sc = blockIdx.x & 7, t = threadIdx.x;
  if (t < 128) aw[t] = attn[((size_t)b << 10) + sc * 128 + t];
  __syncthreads();
  float a0 = 0.f, a1 = 0.f, a2 = 0.f, a3 = 0.f;
  size_t base = ((size_t)b << 20) + ((size_t)(sc * 128) << 10);
  for (int s = 0; s < 128; ++s) {
    float w = aw[s];
    if (ABF16) {
      ushort4 e = *(const ushort4*)((const u16*)encp + base + ((size_t)s << 10) + t * 4);
      a0 += w * bf2f(e.x); a1 += w * bf2f(e.y); a2 += w * bf2f(e.z); a3 += w * bf2f(e.w);
    } else {
      float4 e = *(const float4*)((const float*)encp + base + ((size_t)s << 10) + t * 4);
      a0 += w * e.x; a1 += w * e.y; a2 += w * e.z; a3 += w * e.w;
    }
  }
  float* g = gin + (size_t)b * 1088 + t * 4;
  atomicAdd(g + 0, a0); atomicAdd(g + 1, a1); atomicAdd(g + 2, a2); atomicAdd(g + 3, a3);
}

__global__ void ginx_k(const float* __restrict__ x, float* __restrict__ gin) {
  int i = blockIdx.x * 256 + threadIdx.x;   // 8192
  int b = i >> 6, c = i & 63;
  gin[(size_t)b * 1088 + 1024 + c] = x[i];
}

// ---------------- split-K fp32 GEMM: C += A@W (partial, atomic) ----------------
// 64x64 tile, K-chunk 64 per block (blockIdx.z), 256 threads, 4x4/thread.
__global__ __launch_bounds__(256) void gemm_splitk_k(
    const float* __restrict__ A, int lda,
    const float* __restrict__ W, int ldw,
    float* __restrict__ C, int ldc)
{
  __shared__ float As[64][68];
  __shared__ float Bs[64][64];
  int t = threadIdx.x;
  int m0 = blockIdx.x << 6, n0 = blockIdx.y << 6, k0 = blockIdx.z << 6;
#pragma unroll
  for (int q = 0; q < 4; ++q) {            // A: 64 rows x 16 float4
    int cidx = q * 256 + t;
    int m = cidx >> 4, c4 = cidx & 15;
    float4 v = *(const float4*)(A + (size_t)(m0 + m) * lda + k0 + (c4 << 2));
    As[m][(c4 << 2) + 0] = v.x; As[m][(c4 << 2) + 1] = v.y;
    As[m][(c4 << 2) + 2] = v.z; As[m][(c4 << 2) + 3] = v.w;
  }
#pragma unroll
  for (int q = 0; q < 4; ++q) {            // B: 64 k-rows x 16 float4
    int cidx = q * 256 + t;
    int k = cidx >> 4, nn = cidx & 15;
    *(float4*)&Bs[k][nn << 2] =
        *(const float4*)(W + (size_t)(k0 + k) * ldw + n0 + (nn << 2));
  }
  __syncthreads();
  int tx = t & 15, ty = t >> 4;
  float acc[4][4] = {};
#pragma unroll 8
  for (int k = 0; k < 64; ++k) {
    float a0 = As[(ty << 2) + 0][k], a1 = As[(ty << 2) + 1][k];
    float a2 = As[(ty << 2) + 2][k], a3 = As[(ty << 2) + 3][k];
    float4 bv = *(const float4*)&Bs[k][tx << 2];
    acc[0][0] += a0 * bv.x; acc[0][1] += a0 * bv.y; acc[0][2] += a0 * bv.z; acc[0][3] += a0 * bv.w;
    acc[1][0] += a1 * bv.x; acc[1][1] += a1 * bv.y; acc[1][2] += a1 * bv.z; acc[1][3] += a1 * bv.w;
    acc[2][0] += a2 * bv.x; acc[2][1] += a2 * bv.y; acc[2][2] += a2 * bv.z; acc[2][3] += a2 * bv.w;
    acc[3][0] += a3 * bv.x; acc[3][1] += a3 * bv.y; acc[3][2] += a3 * bv.z; acc[3][3] += a3 * bv.w;
  }
  int col = n0 + (tx << 2);
#pragma unroll
  for (int i = 0; i < 4; ++i) {
    int row = m0 + (ty << 2) + i;
#pragma unroll
    for (int j = 0; j < 4; ++j)
      atomicAdd(C + (size_t)row * ldc + col + j, acc[i][j]);
  }
}

// ---------------- GRU elementwise epilogues ----------------
__global__ void zr_k(const float* __restrict__ xg, const float* __restrict__ hr,
                     const float* __restrict__ hid, const float* __restrict__ bg,
                     float* __restrict__ z, float* __restrict__ rh) {
  int i = blockIdx.x * 256 + threadIdx.x;   // 131072
  int b = i >> 10, n = i & 1023;
  float zv = xg[(size_t)b * 3072 + n] + bg[n] + hr[(size_t)b * 2048 + n];
  float rv = xg[(size_t)b * 3072 + 1024 + n] + bg[1024 + n] + hr[(size_t)b * 2048 + 1024 + n];
  zv = 1.0f / (1.0f + expf(-zv));
  rv = 1.0f / (1.0f + expf(-rv));
  z[i] = zv;
  rh[i] = rv * hid[i];
}

__global__ void state_ep_k(const float* __restrict__ hh, const float* __restrict__ xg,
                           const float* __restrict__ bg, const float* __restrict__ z,
                           const float* __restrict__ hid, float* __restrict__ state) {
  int i = blockIdx.x * 256 + threadIdx.x;   // 131072
  int b = i >> 10, n = i & 1023;
  float val = hh[i] + xg[(size_t)b * 3072 + 2048 + n] + bg[2048 + n];
  float th = tanhf(val);
  float zv = z[i];
  state[i] = zv * hid[i] + (1.0f - zv) * th;
}

__global__ void out_ep_k(float* __restrict__ out, const float* __restrict__ bfc) {
  int i = blockIdx.x * 256 + threadIdx.x;   // 8192
  out[i] += bfc[i & 63];
}

extern "C" void kernel_launch(void* const* d_in, const int* in_sizes, int n_in,
                              void* d_out, int out_size, void* d_ws, size_t ws_size,
                              hipStream_t stream) {
  const float* x    = (const float*)d_in[0];
  const float* hid  = (const float*)d_in[1];
  const float* enc  = (const float*)d_in[2];
  const float* W1   = (const float*)d_in[3];
  const float* b1   = (const float*)d_in[4];
  const float* W2   = (const float*)d_in[5];
  const float* b2   = (const float*)d_in[6];
  const float* Vv   = (const float*)d_in[7];
  // d_in[8] = bV: softmax shift-invariant -> unused
  const float* Wk   = (const float*)d_in[9];
  const float* Wr   = (const float*)d_in[10];
  const float* bg   = (const float*)d_in[11];
  const float* Wfc  = (const float*)d_in[12];
  const float* bfc  = (const float*)d_in[13];

  float* out       = (float*)d_out;
  float* state_out = out + 8192;
  float* attn_out  = out + 8192 + 131072;

  char* ws = (char*)d_ws;
  u16*   w1t   = (u16*)(ws + 0);          // 2 MB
  // --- contiguous atomic-accumulator region (one memset) ---
  float* hb    = (float*)(ws + 2097152);  // 512 KB
  float* score = (float*)(ws + 2621440);  // 512 KB
  float* gin   = (float*)(ws + 3145728);  // 128*1088*4 = 544 KB
  float* xg    = (float*)(ws + 3702784);  // 1.5 MB
  float* hr    = (float*)(ws + 5275648);  // 1 MB
  float* hh    = (float*)(ws + 6324224);  // 512 KB
  // --- non-accumulated ---
  float* z     = (float*)(ws + 6848512);  // 512 KB
  float* rh    = (float*)(ws + 7372800);  // 512 KB
  u16*   enc16 = (u16*)(ws + 8388608);    // 256 MB (path A only)
  const bool pathA = ws_size >= (8388608ULL + 268435456ULL);

  hipMemsetAsync(ws + 2097152, 0, 6848512 - 2097152, stream);  // hb..hh
  hipMemsetAsync(out, 0, 32768, stream);                       // fc accumulator

  conv_w1t_k<<<dim3(32, 32), 256, 0, stream>>>(W1, w1t);
  if (pathA) conv_enc_k<<<4096, 256, 0, stream>>>(enc, enc16);

  // hb = hidden@W2 (biases folded into score epilogue)
  gemm_splitk_k<<<dim3(2, 16, 16), 256, 0, stream>>>(hid, 1024, W2, 1024, hb, 1024);

  if (pathA)
    score_gemm2_k<<<2048, 512, 0, stream>>>(enc16, w1t, hb, b1, b2, Vv, score);
  else
    score_gemm_f32_k<<<8192, 256, 0, stream>>>(enc, w1t, hb, b1, b2, Vv, score);

  softmax_k<<<128, 256, 0, stream>>>(score, attn_out);

  if (pathA) context_k<true><<<1024, 256, 0, stream>>>(enc16, attn_out, gin);
  else       context_k<false><<<1024, 256, 0, stream>>>(enc, attn_out, gin);
  ginx_k<<<32, 256, 0, stream>>>(x, gin);

  // xg = gin@Wk   (bg folded into zr_k / state_ep_k)
  gemm_splitk_k<<<dim3(2, 48, 17), 256, 0, stream>>>(gin, 1088, Wk, 3072, xg, 3072);
  // hr = hidden@Wr[:, :2048]
  gemm_splitk_k<<<dim3(2, 32, 16), 256, 0, stream>>>(hid, 1024, Wr, 3072, hr, 2048);
  zr_k<<<512, 256, 0, stream>>>(xg, hr, hid, bg, z, rh);
  // hh = (r*h)@Wr[:, 2U:]
  gemm_splitk_k<<<dim3(2, 16, 16), 256, 0, stream>>>(rh, 1024, Wr + 2048, 3072, hh, 1024);
  state_ep_k<<<512, 256, 0, stream>>>(hh, xg, bg, z, hid, state_out);
  // out = state@Wfc + bfc
  gemm_splitk_k<<<dim3(2, 1, 16), 256, 0, stream>>>(state_out, 1024, Wfc, 64, out, 64);
  out_ep_k<<<32, 256, 0, stream>>>(out, bfc);
}

// Round 5
// 807.557 us; speedup vs baseline: 1.0174x; 1.0174x over previous
//
#include <hip/hip_runtime.h>
#include <cstdint>

#define B_  128
#define S_  1024
#define U_  1024
#define IN_ 64

typedef unsigned short u16;
typedef __attribute__((ext_vector_type(8))) short short8v;
typedef __attribute__((ext_vector_type(4))) float f32x4;

__device__ __forceinline__ u16 f2bf(float f) {
  uint32_t u = __builtin_bit_cast(uint32_t, f);
  u += 0x7fffu + ((u >> 16) & 1u);
  return (u16)(u >> 16);
}
__device__ __forceinline__ float bf2f(u16 h) {
  uint32_t u = ((uint32_t)h) << 16;
  return __builtin_bit_cast(float, u);
}
// tanh via hw exp + rcp: ~6 VALU ops, |err| ~1e-5 (way under bf16 budget)
__device__ __forceinline__ float fast_tanh(float x) {
  float e = __expf(2.0f * x);
  return 1.0f - 2.0f * __builtin_amdgcn_rcpf(e + 1.0f);
}

// ---------------- enc f32 -> bf16 ----------------
__global__ void conv_enc_k(const float* __restrict__ in, u16* __restrict__ out) {
  size_t tid = (size_t)blockIdx.x * blockDim.x + threadIdx.x;
  size_t stride = (size_t)gridDim.x * blockDim.x;
  const size_t n8 = (size_t)B_ * S_ * U_ / 8;
  for (size_t p = tid; p < n8; p += stride) {
    const float* src = in + p * 8;
    float4 a = *(const float4*)src;
    float4 b = *(const float4*)(src + 4);
    short8v h;
    h[0] = (short)f2bf(a.x); h[1] = (short)f2bf(a.y);
    h[2] = (short)f2bf(a.z); h[3] = (short)f2bf(a.w);
    h[4] = (short)f2bf(b.x); h[5] = (short)f2bf(b.y);
    h[6] = (short)f2bf(b.z); h[7] = (short)f2bf(b.w);
    *(short8v*)(out + p * 8) = h;
  }
}

// ---------------- W1 (K x N) -> W1^T bf16 (N x K) ----------------
__global__ void conv_w1t_k(const float* __restrict__ W1, u16* __restrict__ w1t) {
  __shared__ float tile[32][33];
  int tx = threadIdx.x & 31, tg = threadIdx.x >> 5;  // 32 x 8
  int nb = blockIdx.x << 5, kb = blockIdx.y << 5;
#pragma unroll
  for (int i = 0; i < 4; ++i)
    tile[tg + i * 8][tx] = W1[(size_t)(kb + tg + i * 8) * U_ + nb + tx];
  __syncthreads();
#pragma unroll
  for (int i = 0; i < 4; ++i)
    w1t[(size_t)(nb + tg + i * 8) * U_ + kb + tx] = f2bf(tile[tx][tg + i * 8]);
}

// ---------------- fused score GEMM v4: 256x256 tile, m201-style 8-phase ----
// score[r] = sum_n tanh( (enc @ W1)[r,n] + b1[n] + b2[n] + hb[b(r),n] ) * V[n]
// 8 waves (2M x 4N), per-wave 128x64 output, BK=64, 2 LDS double-buffers
// (2 x 64KB). Each buffer: A-kh0 | A-kh1 | B-kh0 | B-kh1, each 256x32 bf16
// (16KB "half-tile"). Per K-tile, 4 phases; phase (M2, KS) = (mi-half,
// k-slice) computes a DISJOINT acc quadrant (16 MFMA), so consecutive
// phases' MFMA bursts are dependency-free and the matrix pipe never drains.
// Per phase: {ds_read 8 or 4 frags; stage 1 half-tile of K-tile t+1;
// [vmcnt(4) at phases 2,4]; s_barrier; lgkmcnt(0); sched_barrier; setprio(1);
// 16 MFMA; setprio(0); s_barrier}. vmcnt never 0 in the main loop.
// Swizzle: within each 64B row, 16B-chunk c holds global chunk
// c ^ ((row>>1)&3) (same involution at stage-src and read; 2-way max = free).
// Stage ledger (2 loads/half-tile/wave): t.ph1 stages A0(t+1), ph2 B0(t+1)
// [vmcnt(4) drains A1(t),B1(t) for ph3], ph3 A1(t+1), ph4 B1(t+1) [vmcnt(4)
// drains A0(t+1),B0(t+1) for (t+1).ph1]. Overwrites trail last reads by >=3
// barriers.
__global__ __launch_bounds__(512, 1) void score_gemm2_k(
    const u16* __restrict__ encb, const u16* __restrict__ w1t,
    const float* __restrict__ hb, const float* __restrict__ b1,
    const float* __restrict__ b2, const float* __restrict__ Vv,
    float* __restrict__ score)
{
  __shared__ __align__(16) char lds[131072];   // 2 bufs x (A 32KB + B 32KB)
  const int tid  = threadIdx.x;
  const int lane = tid & 63;
  const int wid  = tid >> 6;                   // 0..7
  const int wm = wid >> 2, wn = wid & 3;
  const int r16 = lane & 15, g4 = lane >> 4;

  // XCD-aware bijective swizzle (2048 % 8 == 0), n-inner for A-tile L2 reuse
  int bid = blockIdx.x;
  int logical = (bid & 7) * 256 + (bid >> 3);
  const int row0 = (logical >> 2) << 8;        // M-tile * 256
  const int n0   = (logical & 3) << 8;         // N-tile * 256

  // read-side constants
  const int cx   = (g4 ^ ((r16 >> 1) & 3)) << 4;     // swizzled 16B chunk
  const int arow = (wm * 128 + r16) * 64 + cx;       // + (M2*4+mi)*1024
  const int brow = (wn * 64  + r16) * 64 + cx;       // + ni*1024 (in B region)

  // stage-side per-thread global base pointers (pre-swizzled source)
  const int jsw  = (tid & 3) ^ ((tid >> 3) & 3);     // inverse-swizzled col chunk
  const u16* pA0 = encb + (((size_t)(row0 + (tid >> 2))) << 10) + jsw * 8;
  const u16* pA1 = pA0 + (size_t)128 * 1024;
  const u16* pB0 = w1t  + (((size_t)(n0   + (tid >> 2))) << 10) + jsw * 8;
  const u16* pB1 = pB0 + (size_t)128 * 1024;

  f32x4 acc[8][4] = {};
  short8v bfr[4];

#define STAGE(PTR0, PTR1, REGOFF, KOFF) do {                                   \
    const int _wb = _np + (REGOFF) + (wid << 10);                              \
    __builtin_amdgcn_global_load_lds(                                          \
        (const __attribute__((address_space(1))) void*)((PTR0) + (KOFF)),      \
        (__attribute__((address_space(3))) void*)(lds + _wb), 16, 0, 0);       \
    __builtin_amdgcn_global_load_lds(                                          \
        (const __attribute__((address_space(1))) void*)((PTR1) + (KOFF)),      \
        (__attribute__((address_space(3))) void*)(lds + _wb + 8192), 16, 0, 0);\
  } while (0)

  // PHASE: M2 = mi-half (0/1), KS = k-slice (0/1); stages half (SMAT,KS) of
  // K-tile t+1 when DO_STAGE; VM: -1 none, 4 -> vmcnt(4), 0 -> vmcnt(0).
#define PHASE(M2, KS, DO_STAGE, SPTR0, SPTR1, SREG, VM) do {                   \
    short8v af[4];                                                             \
    { const char* _ab = lds + _pb + (KS) * 16384;                              \
      _Pragma("unroll")                                                        \
      for (int mi = 0; mi < 4; ++mi)                                           \
        af[mi] = *(const short8v*)(_ab + arow + ((M2) * 4 + mi) * 1024); }     \
    if ((M2) == 0) {                                                           \
      const char* _bb = lds + _pb + 32768 + (KS) * 16384;                      \
      _Pragma("unroll")                                                        \
      for (int ni = 0; ni < 4; ++ni)                                           \
        bfr[ni] = *(const short8v*)(_bb + brow + ni * 1024); }                 \
    if (DO_STAGE) { STAGE(SPTR0, SPTR1, SREG, _kbase + (KS) * 32); }           \
    if ((VM) == 4)      asm volatile("s_waitcnt vmcnt(4)" ::: "memory");       \
    else if ((VM) == 0) asm volatile("s_waitcnt vmcnt(0)" ::: "memory");       \
    __builtin_amdgcn_s_barrier();                                              \
    asm volatile("s_waitcnt lgkmcnt(0)" ::: "memory");                         \
    __builtin_amdgcn_sched_barrier(0);                                         \
    __builtin_amdgcn_s_setprio(1);                                             \
    _Pragma("unroll")                                                          \
    for (int mi = 0; mi < 4; ++mi)                                             \
      _Pragma("unroll")                                                        \
      for (int ni = 0; ni < 4; ++ni)                                           \
        acc[(M2) * 4 + mi][ni] = __builtin_amdgcn_mfma_f32_16x16x32_bf16(      \
            af[mi], bfr[ni], acc[(M2) * 4 + mi][ni], 0, 0, 0);                 \
    __builtin_amdgcn_s_setprio(0);                                             \
    __builtin_amdgcn_s_barrier();                                              \
  } while (0)

  // prologue: stage K-tile 0 (A0,B0,A1,B1) into buf0; drain A0,B0 (leave 4)
  {
    const int _np = 0;
    STAGE(pA0, pA1, 0,     0);
    STAGE(pB0, pB1, 32768, 0);
    STAGE(pA0, pA1, 16384, 32);
    STAGE(pB0, pB1, 49152, 32);
  }
  asm volatile("s_waitcnt vmcnt(4)" ::: "memory");
  __builtin_amdgcn_s_barrier();

  // main loop: K-tiles 0..14 stage K-tile t+1
  for (int t = 0; t < 15; ++t) {
    const int _pb = (t & 1) << 16;
    const int _np = _pb ^ 65536;
    const size_t _kbase = (size_t)(t + 1) << 6;         // element col of K-tile t+1
    PHASE(0, 0, 1, pA0, pA1, 0,     -1);
    PHASE(1, 0, 1, pB0, pB1, 32768,  4);
    PHASE(0, 1, 1, pA0, pA1, 16384, -1);
    PHASE(1, 1, 1, pB0, pB1, 49152,  4);
  }
  // tail K-tile 15: no staging; drain remaining A1(15),B1(15) before ph3
  {
    const int _pb = (15 & 1) << 16;
    const int _np = 0; const size_t _kbase = 0; (void)_np; (void)_kbase;
    PHASE(0, 0, 0, pA0, pA1, 0, -1);
    PHASE(1, 0, 0, pA0, pA1, 0,  0);
    PHASE(0, 1, 0, pA0, pA1, 0, -1);
    PHASE(1, 1, 0, pA0, pA1, 0, -1);
  }
#undef PHASE
#undef STAGE

  // ---- epilogue: tanh(+hb+b1+b2) * V, row-reduce over 16 lanes, atomicAdd ----
  const int b = row0 >> 10;                 // 256-row tile never crosses batch
  float vv[4], hbv[4];
#pragma unroll
  for (int ni = 0; ni < 4; ++ni) {
    int col = n0 + (wn << 6) + (ni << 4) + r16;
    vv[ni]  = Vv[col];
    hbv[ni] = hb[(b << 10) + col] + b1[col] + b2[col];
  }
  float rowsum[8][4];
#pragma unroll
  for (int mi = 0; mi < 8; ++mi)
#pragma unroll
    for (int j = 0; j < 4; ++j) rowsum[mi][j] = 0.0f;
#pragma unroll
  for (int mi = 0; mi < 8; ++mi)
#pragma unroll
    for (int ni = 0; ni < 4; ++ni)
#pragma unroll
      for (int j = 0; j < 4; ++j)
        rowsum[mi][j] += fast_tanh(acc[mi][ni][j] + hbv[ni]) * vv[ni];
#pragma unroll
  for (int mi = 0; mi < 8; ++mi)
#pragma unroll
    for (int j = 0; j < 4; ++j) {
      float rs = rowsum[mi][j];
      rs += __shfl_xor(rs, 1);
      rs += __shfl_xor(rs, 2);
      rs += __shfl_xor(rs, 4);
      rs += __shfl_xor(rs, 8);
      if (r16 == 0)
        atomicAdd(score + row0 + (wm << 7) + (mi << 4) + (g4 << 2) + j, rs);
    }
}

// ---------------- fallback fp32-input score GEMM (path B only) ----------------
__global__ __launch_bounds__(256) void score_gemm_f32_k(
    const float* __restrict__ encf, const u16* __restrict__ w1t,
    const float* __restrict__ hb, const float* __restrict__ b1,
    const float* __restrict__ b2, const float* __restrict__ Vv,
    float* __restrict__ score)
{
  __shared__ __align__(16) char lds[32768];
  const int tid  = threadIdx.x;
  const int lane = tid & 63;
  const int wid  = tid >> 6;
  const int wm = wid >> 1, wn = wid & 1;
  const int r16 = lane & 15, g4 = lane >> 4;
  int bid = blockIdx.x;
  int logical = (bid & 7) * 1024 + (bid >> 3);
  const int row0 = (logical >> 3) << 7;
  const int n0   = (logical & 7) << 7;
  f32x4 acc[4][4] = {};
  for (int kk = 0; kk < U_; kk += 64) {
#pragma unroll
    for (int qi = 0; qi < 4; ++qi) {
      int q = 16 + wid * 4 + qi;
      int n = ((q - 16) << 3) + (lane >> 3);
      int c = lane & 7;
      int j = c ^ (n & 7);
      const u16* src = w1t + (((size_t)(n0 + n)) << 10) + kk + (j << 3);
      __builtin_amdgcn_global_load_lds(
          (const __attribute__((address_space(1))) void*)src,
          (__attribute__((address_space(3))) void*)(lds + (q << 10)), 16, 0, 0);
    }
#pragma unroll
    for (int i = 0; i < 4; ++i) {
      int cg = tid * 4 + i;
      int r = cg >> 3, c = cg & 7;
      int j = c ^ (r & 7);
      const float* g = encf + (((size_t)(row0 + r)) << 10) + kk + (j << 3);
      float4 a = *(const float4*)g;
      float4 b = *(const float4*)(g + 4);
      short8v h;
      h[0] = (short)f2bf(a.x); h[1] = (short)f2bf(a.y);
      h[2] = (short)f2bf(a.z); h[3] = (short)f2bf(a.w);
      h[4] = (short)f2bf(b.x); h[5] = (short)f2bf(b.y);
      h[6] = (short)f2bf(b.z); h[7] = (short)f2bf(b.w);
      *(short8v*)(lds + (cg << 4)) = h;
    }
    __syncthreads();
#pragma unroll
    for (int ks = 0; ks < 2; ++ks) {
      short8v af[4], bf[4];
#pragma unroll
      for (int mi = 0; mi < 4; ++mi) {
        int row = (wm << 6) + (mi << 4) + r16;
        int jx = (ks << 2) + g4;
        af[mi] = *(const short8v*)(lds + (row << 7) + ((jx ^ (row & 7)) << 4));
      }
#pragma unroll
      for (int ni = 0; ni < 4; ++ni) {
        int n = (wn << 6) + (ni << 4) + r16;
        int jx = (ks << 2) + g4;
        bf[ni] = *(const short8v*)(lds + 16384 + (n << 7) + ((jx ^ (n & 7)) << 4));
      }
#pragma unroll
      for (int mi = 0; mi < 4; ++mi)
#pragma unroll
        for (int ni = 0; ni < 4; ++ni)
          acc[mi][ni] = __builtin_amdgcn_mfma_f32_16x16x32_bf16(af[mi], bf[ni], acc[mi][ni], 0, 0, 0);
    }
    __syncthreads();
  }
  const int b = row0 >> 10;
  float vv[4], hbv[4];
#pragma unroll
  for (int ni = 0; ni < 4; ++ni) {
    int col = n0 + (wn << 6) + (ni << 4) + r16;
    vv[ni]  = Vv[col];
    hbv[ni] = hb[(b << 10) + col] + b1[col] + b2[col];
  }
  float rowsum[4][4];
#pragma unroll
  for (int mi = 0; mi < 4; ++mi)
#pragma unroll
    for (int j = 0; j < 4; ++j) rowsum[mi][j] = 0.0f;
#pragma unroll
  for (int mi = 0; mi < 4; ++mi)
#pragma unroll
    for (int ni = 0; ni < 4; ++ni)
#pragma unroll
      for (int j = 0; j < 4; ++j)
        rowsum[mi][j] += fast_tanh(acc[mi][ni][j] + hbv[ni]) * vv[ni];
#pragma unroll
  for (int mi = 0; mi < 4; ++mi)
#pragma unroll
    for (int j = 0; j < 4; ++j) {
      float rs = rowsum[mi][j];
      rs += __shfl_xor(rs, 1);
      rs += __shfl_xor(rs, 2);
      rs += __shfl_xor(rs, 4);
      rs += __shfl_xor(rs, 8);
      if (r16 == 0)
        atomicAdd(score + row0 + (wm << 6) + (mi << 4) + (g4 << 2) + j, rs);
    }
}

// ---------------- softmax over S per batch ----------------
__global__ void softmax_k(const float* __restrict__ score, float* __restrict__ attn) {
  __shared__ float red[8];
  int b = blockIdx.x, t = threadIdx.x;     // 256 threads, 4 vals each
  float4 v = ((const float4*)(score + ((size_t)b << 10)))[t];
  float m = fmaxf(fmaxf(v.x, v.y), fmaxf(v.z, v.w));
  for (int o = 1; o < 64; o <<= 1) m = fmaxf(m, __shfl_xor(m, o));
  if ((t & 63) == 0) red[t >> 6] = m;
  __syncthreads();
  m = fmaxf(fmaxf(red[0], red[1]), fmaxf(red[2], red[3]));
  float e0 = expf(v.x - m), e1 = expf(v.y - m), e2 = expf(v.z - m), e3 = expf(v.w - m);
  float s = e0 + e1 + e2 + e3;
  for (int o = 1; o < 64; o <<= 1) s += __shfl_xor(s, o);
  if ((t & 63) == 0) red[4 + (t >> 6)] = s;
  __syncthreads();
  s = red[4] + red[5] + red[6] + red[7];
  float inv = 1.0f / s;
  float4 o4; o4.x = e0 * inv; o4.y = e1 * inv; o4.z = e2 * inv; o4.w = e3 * inv;
  ((float4*)(attn + ((size_t)b << 10)))[t] = o4;
}

// ---------------- context = attn^T @ enc  (accumulate into gin[:, :1024]) ----------------
template<bool ABF16>
__global__ void context_k(const void* __restrict__ encp, const float* __restrict__ attn,
                          float* __restrict__ gin) {
  __shared__ float aw[128];
  int b = blockIdx.x >> 3, sc = blockIdx.x & 7, t = threadIdx.x;
  if (t < 128) aw[t] = attn[((size_t)b << 10) + sc * 128 + t];
  __syncthreads();
  float a0 = 0.f, a1 = 0.f, a2 = 0.f, a3 = 0.f;
  size_t base = ((size_t)b << 20) + ((size_t)(sc * 128) << 10);
  for (int s = 0; s < 128; ++s) {
    float w = aw[s];
    if (ABF16) {
      ushort4 e = *(const ushort4*)((const u16*)encp + base + ((size_t)s << 10) + t * 4);
      a0 += w * bf2f(e.x); a1 += w * bf2f(e.y); a2 += w * bf2f(e.z); a3 += w * bf2f(e.w);
    } else {
      float4 e = *(const float4*)((const float*)encp + base + ((size_t)s << 10) + t * 4);
      a0 += w * e.x; a1 += w * e.y; a2 += w * e.z; a3 += w * e.w;
    }
  }
  float* g = gin + (size_t)b * 1088 + t * 4;
  atomicAdd(g + 0, a0); atomicAdd(g + 1, a1); atomicAdd(g + 2, a2); atomicAdd(g + 3, a3);
}

__global__ void ginx_k(const float* __restrict__ x, float* __restrict__ gin) {
  int i = blockIdx.x * 256 + threadIdx.x;   // 8192
  int b = i >> 6, c = i & 63;
  gin[(size_t)b * 1088 + 1024 + c] = x[i];
}

// ---------------- split-K fp32 GEMM: C += A@W (partial, atomic) ----------------
// 64x64 tile, K-chunk 64 per block (blockIdx.z), 256 threads, 4x4/thread.
__global__ __launch_bounds__(256) void gemm_splitk_k(
    const float* __restrict__ A, int lda,
    const float* __restrict__ W, int ldw,
    float* __restrict__ C, int ldc)
{
  __shared__ float As[64][68];
  __shared__ float Bs[64][64];
  int t = threadIdx.x;
  int m0 = blockIdx.x << 6, n0 = blockIdx.y << 6, k0 = blockIdx.z << 6;
#pragma unroll
  for (int q = 0; q < 4; ++q) {            // A: 64 rows x 16 float4
    int cidx = q * 256 + t;
    int m = cidx >> 4, c4 = cidx & 15;
    float4 v = *(const float4*)(A + (size_t)(m0 + m) * lda + k0 + (c4 << 2));
    As[m][(c4 << 2) + 0] = v.x; As[m][(c4 << 2) + 1] = v.y;
    As[m][(c4 << 2) + 2] = v.z; As[m][(c4 << 2) + 3] = v.w;
  }
#pragma unroll
  for (int q = 0; q < 4; ++q) {            // B: 64 k-rows x 16 float4
    int cidx = q * 256 + t;
    int k = cidx >> 4, nn = cidx & 15;
    *(float4*)&Bs[k][nn << 2] =
        *(const float4*)(W + (size_t)(k0 + k) * ldw + n0 + (nn << 2));
  }
  __syncthreads();
  int tx = t & 15, ty = t >> 4;
  float acc[4][4] = {};
#pragma unroll 8
  for (int k = 0; k < 64; ++k) {
    float a0 = As[(ty << 2) + 0][k], a1 = As[(ty << 2) + 1][k];
    float a2 = As[(ty << 2) + 2][k], a3 = As[(ty << 2) + 3][k];
    float4 bv = *(const float4*)&Bs[k][tx << 2];
    acc[0][0] += a0 * bv.x; acc[0][1] += a0 * bv.y; acc[0][2] += a0 * bv.z; acc[0][3] += a0 * bv.w;
    acc[1][0] += a1 * bv.x; acc[1][1] += a1 * bv.y; acc[1][2] += a1 * bv.z; acc[1][3] += a1 * bv.w;
    acc[2][0] += a2 * bv.x; acc[2][1] += a2 * bv.y; acc[2][2] += a2 * bv.z; acc[2][3] += a2 * bv.w;
    acc[3][0] += a3 * bv.x; acc[3][1] += a3 * bv.y; acc[3][2] += a3 * bv.z; acc[3][3] += a3 * bv.w;
  }
  int col = n0 + (tx << 2);
#pragma unroll
  for (int i = 0; i < 4; ++i) {
    int row = m0 + (ty << 2) + i;
#pragma unroll
    for (int j = 0; j < 4; ++j)
      atomicAdd(C + (size_t)row * ldc + col + j, acc[i][j]);
  }
}

// ---------------- GRU elementwise epilogues ----------------
__global__ void zr_k(const float* __restrict__ xg, const float* __restrict__ hr,
                     const float* __restrict__ hid, const float* __restrict__ bg,
                     float* __restrict__ z, float* __restrict__ rh) {
  int i = blockIdx.x * 256 + threadIdx.x;   // 131072
  int b = i >> 10, n = i & 1023;
  float zv = xg[(size_t)b * 3072 + n] + bg[n] + hr[(size_t)b * 2048 + n];
  float rv = xg[(size_t)b * 3072 + 1024 + n] + bg[1024 + n] + hr[(size_t)b * 2048 + 1024 + n];
  zv = 1.0f / (1.0f + expf(-zv));
  rv = 1.0f / (1.0f + expf(-rv));
  z[i] = zv;
  rh[i] = rv * hid[i];
}

__global__ void state_ep_k(const float* __restrict__ hh, const float* __restrict__ xg,
                           const float* __restrict__ bg, const float* __restrict__ z,
                           const float* __restrict__ hid, float* __restrict__ state) {
  int i = blockIdx.x * 256 + threadIdx.x;   // 131072
  int b = i >> 10, n = i & 1023;
  float val = hh[i] + xg[(size_t)b * 3072 + 2048 + n] + bg[2048 + n];
  float th = tanhf(val);
  float zv = z[i];
  state[i] = zv * hid[i] + (1.0f - zv) * th;
}

__global__ void out_ep_k(float* __restrict__ out, const float* __restrict__ bfc) {
  int i = blockIdx.x * 256 + threadIdx.x;   // 8192
  out[i] += bfc[i & 63];
}

extern "C" void kernel_launch(void* const* d_in, const int* in_sizes, int n_in,
                              void* d_out, int out_size, void* d_ws, size_t ws_size,
                              hipStream_t stream) {
  const float* x    = (const float*)d_in[0];
  const float* hid  = (const float*)d_in[1];
  const float* enc  = (const float*)d_in[2];
  const float* W1   = (const float*)d_in[3];
  const float* b1   = (const float*)d_in[4];
  const float* W2   = (const float*)d_in[5];
  const float* b2   = (const float*)d_in[6];
  const float* Vv   = (const float*)d_in[7];
  // d_in[8] = bV: softmax shift-invariant -> unused
  const float* Wk   = (const float*)d_in[9];
  const float* Wr   = (const float*)d_in[10];
  const float* bg   = (const float*)d_in[11];
  const float* Wfc  = (const float*)d_in[12];
  const float* bfc  = (const float*)d_in[13];

  float* out       = (float*)d_out;
  float* state_out = out + 8192;
  float* attn_out  = out + 8192 + 131072;

  char* ws = (char*)d_ws;
  u16*   w1t   = (u16*)(ws + 0);          // 2 MB
  // --- contiguous atomic-accumulator region (one memset) ---
  float* hb    = (float*)(ws + 2097152);  // 512 KB
  float* score = (float*)(ws + 2621440);  // 512 KB
  float* gin   = (float*)(ws + 3145728);  // 128*1088*4 = 544 KB
  float* xg    = (float*)(ws + 3702784);  // 1.5 MB
  float* hr    = (float*)(ws + 5275648);  // 1 MB
  float* hh    = (float*)(ws + 6324224);  // 512 KB
  // --- non-accumulated ---
  float* z     = (float*)(ws + 6848512);  // 512 KB
  float* rh    = (float*)(ws + 7372800);  // 512 KB
  u16*   enc16 = (u16*)(ws + 8388608);    // 256 MB (path A only)
  const bool pathA = ws_size >= (8388608ULL + 268435456ULL);

  hipMemsetAsync(ws + 2097152, 0, 6848512 - 2097152, stream);  // hb..hh
  hipMemsetAsync(out, 0, 32768, stream);                       // fc accumulator

  conv_w1t_k<<<dim3(32, 32), 256, 0, stream>>>(W1, w1t);
  if (pathA) conv_enc_k<<<4096, 256, 0, stream>>>(enc, enc16);

  // hb = hidden@W2 (biases folded into score epilogue)
  gemm_splitk_k<<<dim3(2, 16, 16), 256, 0, stream>>>(hid, 1024, W2, 1024, hb, 1024);

  if (pathA)
    score_gemm2_k<<<2048, 512, 0, stream>>>(enc16, w1t, hb, b1, b2, Vv, score);
  else
    score_gemm_f32_k<<<8192, 256, 0, stream>>>(enc, w1t, hb, b1, b2, Vv, score);

  softmax_k<<<128, 256, 0, stream>>>(score, attn_out);

  if (pathA) context_k<true><<<1024, 256, 0, stream>>>(enc16, attn_out, gin);
  else       context_k<false><<<1024, 256, 0, stream>>>(enc, attn_out, gin);
  ginx_k<<<32, 256, 0, stream>>>(x, gin);

  // xg = gin@Wk   (bg folded into zr_k / state_ep_k)
  gemm_splitk_k<<<dim3(2, 48, 17), 256, 0, stream>>>(gin, 1088, Wk, 3072, xg, 3072);
  // hr = hidden@Wr[:, :2048]
  gemm_splitk_k<<<dim3(2, 32, 16), 256, 0, stream>>>(hid, 1024, Wr, 3072, hr, 2048);
  zr_k<<<512, 256, 0, stream>>>(xg, hr, hid, bg, z, rh);
  // hh = (r*h)@Wr[:, 2U:]
  gemm_splitk_k<<<dim3(2, 16, 16), 256, 0, stream>>>(rh, 1024, Wr + 2048, 3072, hh, 1024);
  state_ep_k<<<512, 256, 0, stream>>>(hh, xg, bg, z, hid, state_out);
  // out = state@Wfc + bfc
  gemm_splitk_k<<<dim3(2, 1, 16), 256, 0, stream>>>(state_out, 1024, Wfc, 64, out, 64);
  out_ep_k<<<32, 256, 0, stream>>>(out, bfc);
}

// Round 6
// 786.966 us; speedup vs baseline: 1.0441x; 1.0262x over previous
//
#include <hip/hip_runtime.h>
#include <cstdint>

#define B_  128
#define S_  1024
#define U_  1024
#define IN_ 64

typedef unsigned short u16;
typedef __attribute__((ext_vector_type(8))) short short8v;
typedef __attribute__((ext_vector_type(4))) float f32x4;

__device__ __forceinline__ u16 f2bf(float f) {
  uint32_t u = __builtin_bit_cast(uint32_t, f);
  u += 0x7fffu + ((u >> 16) & 1u);
  return (u16)(u >> 16);
}
__device__ __forceinline__ float bf2f(u16 h) {
  uint32_t u = ((uint32_t)h) << 16;
  return __builtin_bit_cast(float, u);
}
// tanh via hw exp + rcp: ~6 VALU ops, |err| ~1e-5 (way under bf16 budget)
__device__ __forceinline__ float fast_tanh(float x) {
  float e = __expf(2.0f * x);
  return 1.0f - 2.0f * __builtin_amdgcn_rcpf(e + 1.0f);
}

// ---------------- enc f32 -> bf16 ----------------
__global__ void conv_enc_k(const float* __restrict__ in, u16* __restrict__ out) {
  size_t tid = (size_t)blockIdx.x * blockDim.x + threadIdx.x;
  size_t stride = (size_t)gridDim.x * blockDim.x;
  const size_t n8 = (size_t)B_ * S_ * U_ / 8;
  for (size_t p = tid; p < n8; p += stride) {
    const float* src = in + p * 8;
    float4 a = *(const float4*)src;
    float4 b = *(const float4*)(src + 4);
    short8v h;
    h[0] = (short)f2bf(a.x); h[1] = (short)f2bf(a.y);
    h[2] = (short)f2bf(a.z); h[3] = (short)f2bf(a.w);
    h[4] = (short)f2bf(b.x); h[5] = (short)f2bf(b.y);
    h[6] = (short)f2bf(b.z); h[7] = (short)f2bf(b.w);
    *(short8v*)(out + p * 8) = h;
  }
}

// ---------------- W1 (K x N) -> W1^T bf16 (N x K) ----------------
__global__ void conv_w1t_k(const float* __restrict__ W1, u16* __restrict__ w1t) {
  __shared__ float tile[32][33];
  int tx = threadIdx.x & 31, tg = threadIdx.x >> 5;  // 32 x 8
  int nb = blockIdx.x << 5, kb = blockIdx.y << 5;
#pragma unroll
  for (int i = 0; i < 4; ++i)
    tile[tg + i * 8][tx] = W1[(size_t)(kb + tg + i * 8) * U_ + nb + tx];
  __syncthreads();
#pragma unroll
  for (int i = 0; i < 4; ++i)
    w1t[(size_t)(nb + tg + i * 8) * U_ + kb + tx] = f2bf(tile[tx][tg + i * 8]);
}

// ---------------- fused score GEMM v5: 256x256 tile, 1-barrier phases ----
// score[r] = sum_n tanh( (enc @ W1)[r,n] + b1[n] + b2[n] + hb[b(r),n] ) * V[n]
// 8 waves (2M x 4N), per-wave 128x64 output, BK=64, 2 LDS double-buffers
// (2 x 64KB): A-kh0 | A-kh1 | B-kh0 | B-kh1, each 256x32 bf16 per buffer.
// 4 phases per K-tile, ONE barrier per phase:
//   [ds_read frags p] [stage 1 half of tile t+1] [vmcnt(4) at ph2,ph4]
//   [s_barrier] [lgkmcnt(0); sched_barrier] [setprio(1); 16 MFMA; setprio(0)]
// No trailing barrier: the first wave to finish its MFMA burst immediately
// issues the next phase's ds_reads while other waves still feed the matrix
// pipe (LDS port hides under the MFMA shadow). Hazard ledger:
//  - RAW staged halves: A1B1(t) drained by stager's vmcnt(4)@t.ph2 (8 out ->
//    4), read at t.ph3/ph4 whose ds_reads issue after the t.ph3 barrier >
//    every wave's t.ph2 vmcnt. A0B0(t+1) drained @t.ph4, read at t+1.ph1/ph2
//    after the t+1.ph1 barrier. Never-0 vmcnt in main loop.
//  - WAR: stage@t.ph1 overwrites region last ds_read at t-1.ph1; those reads
//    completed at reader's lgkmcnt(0) pre-MFMA, >=3 barriers earlier.
// Swizzle: 16B-chunk c holds global chunk c ^ ((row>>1)&3) (same involution
// at stage-src and read; 2-way max bank aliasing = free).
__global__ __launch_bounds__(512, 1) void score_gemm2_k(
    const u16* __restrict__ encb, const u16* __restrict__ w1t,
    const float* __restrict__ hb, const float* __restrict__ b1,
    const float* __restrict__ b2, const float* __restrict__ Vv,
    float* __restrict__ score)
{
  __shared__ __align__(16) char lds[131072];   // 2 bufs x (A 32KB + B 32KB)
  const int tid  = threadIdx.x;
  const int lane = tid & 63;
  const int wid  = tid >> 6;                   // 0..7
  const int wm = wid >> 2, wn = wid & 3;
  const int r16 = lane & 15, g4 = lane >> 4;

  // XCD-aware bijective swizzle (2048 % 8 == 0), n-inner for A-tile L2 reuse
  int bid = blockIdx.x;
  int logical = (bid & 7) * 256 + (bid >> 3);
  const int row0 = (logical >> 2) << 8;        // M-tile * 256
  const int n0   = (logical & 3) << 8;         // N-tile * 256

  // read-side constants
  const int cx   = (g4 ^ ((r16 >> 1) & 3)) << 4;     // swizzled 16B chunk
  const int arow = (wm * 128 + r16) * 64 + cx;       // + (M2*4+mi)*1024
  const int brow = (wn * 64  + r16) * 64 + cx;       // + ni*1024 (in B region)

  // stage-side per-thread global base pointers (pre-swizzled source)
  const int jsw  = (tid & 3) ^ ((tid >> 3) & 3);     // inverse-swizzled col chunk
  const u16* pA0 = encb + (((size_t)(row0 + (tid >> 2))) << 10) + jsw * 8;
  const u16* pA1 = pA0 + (size_t)128 * 1024;
  const u16* pB0 = w1t  + (((size_t)(n0   + (tid >> 2))) << 10) + jsw * 8;
  const u16* pB1 = pB0 + (size_t)128 * 1024;

  f32x4 acc[8][4] = {};
  short8v bfr[4];

#define STAGE(PTR0, PTR1, REGOFF, KOFF) do {                                   \
    const int _wb = _np + (REGOFF) + (wid << 10);                              \
    __builtin_amdgcn_global_load_lds(                                          \
        (const __attribute__((address_space(1))) void*)((PTR0) + (KOFF)),      \
        (__attribute__((address_space(3))) void*)(lds + _wb), 16, 0, 0);       \
    __builtin_amdgcn_global_load_lds(                                          \
        (const __attribute__((address_space(1))) void*)((PTR1) + (KOFF)),      \
        (__attribute__((address_space(3))) void*)(lds + _wb + 8192), 16, 0, 0);\
  } while (0)

  // PHASE: M2 = mi-half (0/1), KS = k-slice (0/1); stages half (SMAT,KS) of
  // K-tile t+1 when DO_STAGE; VM: -1 none, 4 -> vmcnt(4), 0 -> vmcnt(0).
#define PHASE(M2, KS, DO_STAGE, SPTR0, SPTR1, SREG, VM) do {                   \
    short8v af[4];                                                             \
    { const char* _ab = lds + _pb + (KS) * 16384;                              \
      _Pragma("unroll")                                                        \
      for (int mi = 0; mi < 4; ++mi)                                           \
        af[mi] = *(const short8v*)(_ab + arow + ((M2) * 4 + mi) * 1024); }     \
    if ((M2) == 0) {                                                           \
      const char* _bb = lds + _pb + 32768 + (KS) * 16384;                      \
      _Pragma("unroll")                                                        \
      for (int ni = 0; ni < 4; ++ni)                                           \
        bfr[ni] = *(const short8v*)(_bb + brow + ni * 1024); }                 \
    if (DO_STAGE) { STAGE(SPTR0, SPTR1, SREG, _kbase + (KS) * 32); }           \
    if ((VM) == 4)      asm volatile("s_waitcnt vmcnt(4)" ::: "memory");       \
    else if ((VM) == 0) asm volatile("s_waitcnt vmcnt(0)" ::: "memory");       \
    __builtin_amdgcn_s_barrier();                                              \
    asm volatile("s_waitcnt lgkmcnt(0)" ::: "memory");                         \
    __builtin_amdgcn_sched_barrier(0);                                         \
    __builtin_amdgcn_s_setprio(1);                                             \
    _Pragma("unroll")                                                          \
    for (int mi = 0; mi < 4; ++mi)                                             \
      _Pragma("unroll")                                                        \
      for (int ni = 0; ni < 4; ++ni)                                           \
        acc[(M2) * 4 + mi][ni] = __builtin_amdgcn_mfma_f32_16x16x32_bf16(      \
            af[mi], bfr[ni], acc[(M2) * 4 + mi][ni], 0, 0, 0);                 \
    __builtin_amdgcn_s_setprio(0);                                             \
  } while (0)

  // prologue: stage K-tile 0 (A0,B0,A1,B1) into buf0; drain A0,B0 (leave 4)
  {
    const int _np = 0;
    STAGE(pA0, pA1, 0,     0);
    STAGE(pB0, pB1, 32768, 0);
    STAGE(pA0, pA1, 16384, 32);
    STAGE(pB0, pB1, 49152, 32);
  }
  asm volatile("s_waitcnt vmcnt(4)" ::: "memory");
  __builtin_amdgcn_s_barrier();

  // main loop: K-tiles 0..14 stage K-tile t+1
  for (int t = 0; t < 15; ++t) {
    const int _pb = (t & 1) << 16;
    const int _np = _pb ^ 65536;
    const size_t _kbase = (size_t)(t + 1) << 6;         // element col of K-tile t+1
    PHASE(0, 0, 1, pA0, pA1, 0,     -1);
    PHASE(1, 0, 1, pB0, pB1, 32768,  4);
    PHASE(0, 1, 1, pA0, pA1, 16384, -1);
    PHASE(1, 1, 1, pB0, pB1, 49152,  4);
  }
  // tail K-tile 15: no staging; drain remaining A1(15),B1(15) before ph3
  {
    const int _pb = (15 & 1) << 16;
    const int _np = 0; const size_t _kbase = 0; (void)_np; (void)_kbase;
    PHASE(0, 0, 0, pA0, pA1, 0, -1);
    PHASE(1, 0, 0, pA0, pA1, 0,  0);
    PHASE(0, 1, 0, pA0, pA1, 0, -1);
    PHASE(1, 1, 0, pA0, pA1, 0, -1);
  }
#undef PHASE
#undef STAGE

  // ---- epilogue: tanh(+hb+b1+b2) * V, row-reduce over 16 lanes, atomicAdd ----
  const int b = row0 >> 10;                 // 256-row tile never crosses batch
  float vv[4], hbv[4];
#pragma unroll
  for (int ni = 0; ni < 4; ++ni) {
    int col = n0 + (wn << 6) + (ni << 4) + r16;
    vv[ni]  = Vv[col];
    hbv[ni] = hb[(b << 10) + col] + b1[col] + b2[col];
  }
  float rowsum[8][4];
#pragma unroll
  for (int mi = 0; mi < 8; ++mi)
#pragma unroll
    for (int j = 0; j < 4; ++j) rowsum[mi][j] = 0.0f;
#pragma unroll
  for (int mi = 0; mi < 8; ++mi)
#pragma unroll
    for (int ni = 0; ni < 4; ++ni)
#pragma unroll
      for (int j = 0; j < 4; ++j)
        rowsum[mi][j] += fast_tanh(acc[mi][ni][j] + hbv[ni]) * vv[ni];
#pragma unroll
  for (int mi = 0; mi < 8; ++mi)
#pragma unroll
    for (int j = 0; j < 4; ++j) {
      float rs = rowsum[mi][j];
      rs += __shfl_xor(rs, 1);
      rs += __shfl_xor(rs, 2);
      rs += __shfl_xor(rs, 4);
      rs += __shfl_xor(rs, 8);
      if (r16 == 0)
        atomicAdd(score + row0 + (wm << 7) + (mi << 4) + (g4 << 2) + j, rs);
    }
}

// ---------------- fallback fp32-input score GEMM (path B only) ----------------
__global__ __launch_bounds__(256) void score_gemm_f32_k(
    const float* __restrict__ encf, const u16* __restrict__ w1t,
    const float* __restrict__ hb, const float* __restrict__ b1,
    const float* __restrict__ b2, const float* __restrict__ Vv,
    float* __restrict__ score)
{
  __shared__ __align__(16) char lds[32768];
  const int tid  = threadIdx.x;
  const int lane = tid & 63;
  const int wid  = tid >> 6;
  const int wm = wid >> 1, wn = wid & 1;
  const int r16 = lane & 15, g4 = lane >> 4;
  int bid = blockIdx.x;
  int logical = (bid & 7) * 1024 + (bid >> 3);
  const int row0 = (logical >> 3) << 7;
  const int n0   = (logical & 7) << 7;
  f32x4 acc[4][4] = {};
  for (int kk = 0; kk < U_; kk += 64) {
#pragma unroll
    for (int qi = 0; qi < 4; ++qi) {
      int q = 16 + wid * 4 + qi;
      int n = ((q - 16) << 3) + (lane >> 3);
      int c = lane & 7;
      int j = c ^ (n & 7);
      const u16* src = w1t + (((size_t)(n0 + n)) << 10) + kk + (j << 3);
      __builtin_amdgcn_global_load_lds(
          (const __attribute__((address_space(1))) void*)src,
          (__attribute__((address_space(3))) void*)(lds + (q << 10)), 16, 0, 0);
    }
#pragma unroll
    for (int i = 0; i < 4; ++i) {
      int cg = tid * 4 + i;
      int r = cg >> 3, c = cg & 7;
      int j = c ^ (r & 7);
      const float* g = encf + (((size_t)(row0 + r)) << 10) + kk + (j << 3);
      float4 a = *(const float4*)g;
      float4 b = *(const float4*)(g + 4);
      short8v h;
      h[0] = (short)f2bf(a.x); h[1] = (short)f2bf(a.y);
      h[2] = (short)f2bf(a.z); h[3] = (short)f2bf(a.w);
      h[4] = (short)f2bf(b.x); h[5] = (short)f2bf(b.y);
      h[6] = (short)f2bf(b.z); h[7] = (short)f2bf(b.w);
      *(short8v*)(lds + (cg << 4)) = h;
    }
    __syncthreads();
#pragma unroll
    for (int ks = 0; ks < 2; ++ks) {
      short8v af[4], bf[4];
#pragma unroll
      for (int mi = 0; mi < 4; ++mi) {
        int row = (wm << 6) + (mi << 4) + r16;
        int jx = (ks << 2) + g4;
        af[mi] = *(const short8v*)(lds + (row << 7) + ((jx ^ (row & 7)) << 4));
      }
#pragma unroll
      for (int ni = 0; ni < 4; ++ni) {
        int n = (wn << 6) + (ni << 4) + r16;
        int jx = (ks << 2) + g4;
        bf[ni] = *(const short8v*)(lds + 16384 + (n << 7) + ((jx ^ (n & 7)) << 4));
      }
#pragma unroll
      for (int mi = 0; mi < 4; ++mi)
#pragma unroll
        for (int ni = 0; ni < 4; ++ni)
          acc[mi][ni] = __builtin_amdgcn_mfma_f32_16x16x32_bf16(af[mi], bf[ni], acc[mi][ni], 0, 0, 0);
    }
    __syncthreads();
  }
  const int b = row0 >> 10;
  float vv[4], hbv[4];
#pragma unroll
  for (int ni = 0; ni < 4; ++ni) {
    int col = n0 + (wn << 6) + (ni << 4) + r16;
    vv[ni]  = Vv[col];
    hbv[ni] = hb[(b << 10) + col] + b1[col] + b2[col];
  }
  float rowsum[4][4];
#pragma unroll
  for (int mi = 0; mi < 4; ++mi)
#pragma unroll
    for (int j = 0; j < 4; ++j) rowsum[mi][j] = 0.0f;
#pragma unroll
  for (int mi = 0; mi < 4; ++mi)
#pragma unroll
    for (int ni = 0; ni < 4; ++ni)
#pragma unroll
      for (int j = 0; j < 4; ++j)
        rowsum[mi][j] += fast_tanh(acc[mi][ni][j] + hbv[ni]) * vv[ni];
#pragma unroll
  for (int mi = 0; mi < 4; ++mi)
#pragma unroll
    for (int j = 0; j < 4; ++j) {
      float rs = rowsum[mi][j];
      rs += __shfl_xor(rs, 1);
      rs += __shfl_xor(rs, 2);
      rs += __shfl_xor(rs, 4);
      rs += __shfl_xor(rs, 8);
      if (r16 == 0)
        atomicAdd(score + row0 + (wm << 6) + (mi << 4) + (g4 << 2) + j, rs);
    }
}

// ---------------- softmax over S per batch ----------------
__global__ void softmax_k(const float* __restrict__ score, float* __restrict__ attn) {
  __shared__ float red[8];
  int b = blockIdx.x, t = threadIdx.x;     // 256 threads, 4 vals each
  float4 v = ((const float4*)(score + ((size_t)b << 10)))[t];
  float m = fmaxf(fmaxf(v.x, v.y), fmaxf(v.z, v.w));
  for (int o = 1; o < 64; o <<= 1) m = fmaxf(m, __shfl_xor(m, o));
  if ((t & 63) == 0) red[t >> 6] = m;
  __syncthreads();
  m = fmaxf(fmaxf(red[0], red[1]), fmaxf(red[2], red[3]));
  float e0 = expf(v.x - m), e1 = expf(v.y - m), e2 = expf(v.z - m), e3 = expf(v.w - m);
  float s = e0 + e1 + e2 + e3;
  for (int o = 1; o < 64; o <<= 1) s += __shfl_xor(s, o);
  if ((t & 63) == 0) red[4 + (t >> 6)] = s;
  __syncthreads();
  s = red[4] + red[5] + red[6] + red[7];
  float inv = 1.0f / s;
  float4 o4; o4.x = e0 * inv; o4.y = e1 * inv; o4.z = e2 * inv; o4.w = e3 * inv;
  ((float4*)(attn + ((size_t)b << 10)))[t] = o4;
}

// ---------------- context = attn^T @ enc  (accumulate into gin[:, :1024]) ----------------
template<bool ABF16>
__global__ void context_k(const void* __restrict__ encp, const float* __restrict__ attn,
                          float* __restrict__ gin) {
  __shared__ float aw[128];
  int b = blockIdx.x >> 3, sc = blockIdx.x & 7, t = threadIdx.x;
  if (t < 128) aw[t] = attn[((size_t)b << 10) + sc * 128 + t];
  __syncthreads();
  float a0 = 0.f, a1 = 0.f, a2 = 0.f, a3 = 0.f;
  size_t base = ((size_t)b << 20) + ((size_t)(sc * 128) << 10);
  for (int s = 0; s < 128; ++s) {
    float w = aw[s];
    if (ABF16) {
      ushort4 e = *(const ushort4*)((const u16*)encp + base + ((size_t)s << 10) + t * 4);
      a0 += w * bf2f(e.x); a1 += w * bf2f(e.y); a2 += w * bf2f(e.z); a3 += w * bf2f(e.w);
    } else {
      float4 e = *(const float4*)((const float*)encp + base + ((size_t)s << 10) + t * 4);
      a0 += w * e.x; a1 += w * e.y; a2 += w * e.z; a3 += w * e.w;
    }
  }
  float* g = gin + (size_t)b * 1088 + t * 4;
  atomicAdd(g + 0, a0); atomicAdd(g + 1, a1); atomicAdd(g + 2, a2); atomicAdd(g + 3, a3);
}

__global__ void ginx_k(const float* __restrict__ x, float* __restrict__ gin) {
  int i = blockIdx.x * 256 + threadIdx.x;   // 8192
  int b = i >> 6, c = i & 63;
  gin[(size_t)b * 1088 + 1024 + c] = x[i];
}

// ---------------- split-K fp32 GEMM: C += A@W (partial, atomic) ----------------
// 64x64 tile, K-chunk 64 per block (blockIdx.z), 256 threads, 4x4/thread.
__global__ __launch_bounds__(256) void gemm_splitk_k(
    const float* __restrict__ A, int lda,
    const float* __restrict__ W, int ldw,
    float* __restrict__ C, int ldc)
{
  __shared__ float As[64][68];
  __shared__ float Bs[64][64];
  int t = threadIdx.x;
  int m0 = blockIdx.x << 6, n0 = blockIdx.y << 6, k0 = blockIdx.z << 6;
#pragma unroll
  for (int q = 0; q < 4; ++q) {            // A: 64 rows x 16 float4
    int cidx = q * 256 + t;
    int m = cidx >> 4, c4 = cidx & 15;
    float4 v = *(const float4*)(A + (size_t)(m0 + m) * lda + k0 + (c4 << 2));
    As[m][(c4 << 2) + 0] = v.x; As[m][(c4 << 2) + 1] = v.y;
    As[m][(c4 << 2) + 2] = v.z; As[m][(c4 << 2) + 3] = v.w;
  }
#pragma unroll
  for (int q = 0; q < 4; ++q) {            // B: 64 k-rows x 16 float4
    int cidx = q * 256 + t;
    int k = cidx >> 4, nn = cidx & 15;
    *(float4*)&Bs[k][nn << 2] =
        *(const float4*)(W + (size_t)(k0 + k) * ldw + n0 + (nn << 2));
  }
  __syncthreads();
  int tx = t & 15, ty = t >> 4;
  float acc[4][4] = {};
#pragma unroll 8
  for (int k = 0; k < 64; ++k) {
    float a0 = As[(ty << 2) + 0][k], a1 = As[(ty << 2) + 1][k];
    float a2 = As[(ty << 2) + 2][k], a3 = As[(ty << 2) + 3][k];
    float4 bv = *(const float4*)&Bs[k][tx << 2];
    acc[0][0] += a0 * bv.x; acc[0][1] += a0 * bv.y; acc[0][2] += a0 * bv.z; acc[0][3] += a0 * bv.w;
    acc[1][0] += a1 * bv.x; acc[1][1] += a1 * bv.y; acc[1][2] += a1 * bv.z; acc[1][3] += a1 * bv.w;
    acc[2][0] += a2 * bv.x; acc[2][1] += a2 * bv.y; acc[2][2] += a2 * bv.z; acc[2][3] += a2 * bv.w;
    acc[3][0] += a3 * bv.x; acc[3][1] += a3 * bv.y; acc[3][2] += a3 * bv.z; acc[3][3] += a3 * bv.w;
  }
  int col = n0 + (tx << 2);
#pragma unroll
  for (int i = 0; i < 4; ++i) {
    int row = m0 + (ty << 2) + i;
#pragma unroll
    for (int j = 0; j < 4; ++j)
      atomicAdd(C + (size_t)row * ldc + col + j, acc[i][j]);
  }
}

// ---------------- GRU elementwise epilogues ----------------
__global__ void zr_k(const float* __restrict__ xg, const float* __restrict__ hr,
                     const float* __restrict__ hid, const float* __restrict__ bg,
                     float* __restrict__ z, float* __restrict__ rh) {
  int i = blockIdx.x * 256 + threadIdx.x;   // 131072
  int b = i >> 10, n = i & 1023;
  float zv = xg[(size_t)b * 3072 + n] + bg[n] + hr[(size_t)b * 2048 + n];
  float rv = xg[(size_t)b * 3072 + 1024 + n] + bg[1024 + n] + hr[(size_t)b * 2048 + 1024 + n];
  zv = 1.0f / (1.0f + expf(-zv));
  rv = 1.0f / (1.0f + expf(-rv));
  z[i] = zv;
  rh[i] = rv * hid[i];
}

__global__ void state_ep_k(const float* __restrict__ hh, const float* __restrict__ xg,
                           const float* __restrict__ bg, const float* __restrict__ z,
                           const float* __restrict__ hid, float* __restrict__ state) {
  int i = blockIdx.x * 256 + threadIdx.x;   // 131072
  int b = i >> 10, n = i & 1023;
  float val = hh[i] + xg[(size_t)b * 3072 + 2048 + n] + bg[2048 + n];
  float th = tanhf(val);
  float zv = z[i];
  state[i] = zv * hid[i] + (1.0f - zv) * th;
}

__global__ void out_ep_k(float* __restrict__ out, const float* __restrict__ bfc) {
  int i = blockIdx.x * 256 + threadIdx.x;   // 8192
  out[i] += bfc[i & 63];
}

extern "C" void kernel_launch(void* const* d_in, const int* in_sizes, int n_in,
                              void* d_out, int out_size, void* d_ws, size_t ws_size,
                              hipStream_t stream) {
  const float* x    = (const float*)d_in[0];
  const float* hid  = (const float*)d_in[1];
  const float* enc  = (const float*)d_in[2];
  const float* W1   = (const float*)d_in[3];
  const float* b1   = (const float*)d_in[4];
  const float* W2   = (const float*)d_in[5];
  const float* b2   = (const float*)d_in[6];
  const float* Vv   = (const float*)d_in[7];
  // d_in[8] = bV: softmax shift-invariant -> unused
  const float* Wk   = (const float*)d_in[9];
  const float* Wr   = (const float*)d_in[10];
  const float* bg   = (const float*)d_in[11];
  const float* Wfc  = (const float*)d_in[12];
  const float* bfc  = (const float*)d_in[13];

  float* out       = (float*)d_out;
  float* state_out = out + 8192;
  float* attn_out  = out + 8192 + 131072;

  char* ws = (char*)d_ws;
  u16*   w1t   = (u16*)(ws + 0);          // 2 MB
  // --- contiguous atomic-accumulator region (one memset) ---
  float* hb    = (float*)(ws + 2097152);  // 512 KB
  float* score = (float*)(ws + 2621440);  // 512 KB
  float* gin   = (float*)(ws + 3145728);  // 128*1088*4 = 544 KB
  float* xg    = (float*)(ws + 3702784);  // 1.5 MB
  float* hr    = (float*)(ws + 5275648);  // 1 MB
  float* hh    = (float*)(ws + 6324224);  // 512 KB
  // --- non-accumulated ---
  float* z     = (float*)(ws + 6848512);  // 512 KB
  float* rh    = (float*)(ws + 7372800);  // 512 KB
  u16*   enc16 = (u16*)(ws + 8388608);    // 256 MB (path A only)
  const bool pathA = ws_size >= (8388608ULL + 268435456ULL);

  hipMemsetAsync(ws + 2097152, 0, 6848512 - 2097152, stream);  // hb..hh
  hipMemsetAsync(out, 0, 32768, stream);                       // fc accumulator

  conv_w1t_k<<<dim3(32, 32), 256, 0, stream>>>(W1, w1t);
  if (pathA) conv_enc_k<<<4096, 256, 0, stream>>>(enc, enc16);

  // hb = hidden@W2 (biases folded into score epilogue)
  gemm_splitk_k<<<dim3(2, 16, 16), 256, 0, stream>>>(hid, 1024, W2, 1024, hb, 1024);

  if (pathA)
    score_gemm2_k<<<2048, 512, 0, stream>>>(enc16, w1t, hb, b1, b2, Vv, score);
  else
    score_gemm_f32_k<<<8192, 256, 0, stream>>>(enc, w1t, hb, b1, b2, Vv, score);

  softmax_k<<<128, 256, 0, stream>>>(score, attn_out);

  if (pathA) context_k<true><<<1024, 256, 0, stream>>>(enc16, attn_out, gin);
  else       context_k<false><<<1024, 256, 0, stream>>>(enc, attn_out, gin);
  ginx_k<<<32, 256, 0, stream>>>(x, gin);

  // xg = gin@Wk   (bg folded into zr_k / state_ep_k)
  gemm_splitk_k<<<dim3(2, 48, 17), 256, 0, stream>>>(gin, 1088, Wk, 3072, xg, 3072);
  // hr = hidden@Wr[:, :2048]
  gemm_splitk_k<<<dim3(2, 32, 16), 256, 0, stream>>>(hid, 1024, Wr, 3072, hr, 2048);
  zr_k<<<512, 256, 0, stream>>>(xg, hr, hid, bg, z, rh);
  // hh = (r*h)@Wr[:, 2U:]
  gemm_splitk_k<<<dim3(2, 16, 16), 256, 0, stream>>>(rh, 1024, Wr + 2048, 3072, hh, 1024);
  state_ep_k<<<512, 256, 0, stream>>>(hh, xg, bg, z, hid, state_out);
  // out = state@Wfc + bfc
  gemm_splitk_k<<<dim3(2, 1, 16), 256, 0, stream>>>(state_out, 1024, Wfc, 64, out, 64);
  out_ep_k<<<32, 256, 0, stream>>>(out, bfc);
}